// Round 1
// baseline (818.507 us; speedup 1.0000x reference)
//
#include <hip/hip_runtime.h>

typedef unsigned short u16;
typedef __attribute__((ext_vector_type(8))) short short8;
typedef __attribute__((ext_vector_type(4))) short short4v;
typedef __attribute__((ext_vector_type(4))) float floatx4;

#define HD 1024
#define SEQ 4096

__device__ inline u16 f2bf(float f) {
    union { float f; unsigned int i; } c; c.f = f;
    unsigned int r = c.i + 0x7fffu + ((c.i >> 16) & 1u);
    return (u16)(r >> 16);
}

// ---------------- Kernel A: x f32 -> bf16 ----------------
__global__ __launch_bounds__(256) void cvt_kernel(const float* __restrict__ in,
                                                  u16* __restrict__ out, int n4) {
    int idx = blockIdx.x * 256 + threadIdx.x;
    int stride = gridDim.x * 256;
    for (int i = idx; i < n4; i += stride) {
        floatx4 v = ((const floatx4*)in)[i];
        short4v o;
        o[0] = (short)f2bf(v[0]); o[1] = (short)f2bf(v[1]);
        o[2] = (short)f2bf(v[2]); o[3] = (short)f2bf(v[3]);
        ((short4v*)out)[i] = o;
    }
}

// ---------------- Kernel 0: W f32 [k][n] -> Wt bf16 [n][k], 3 matrices ----------------
__global__ __launch_bounds__(256) void wt_kernel(const float* __restrict__ Wq,
                                                 const float* __restrict__ Wk,
                                                 const float* __restrict__ Wv,
                                                 u16* __restrict__ wt) {
    __shared__ u16 tile[64 * 65];
    int z = blockIdx.z;
    const float* W = (z == 0) ? Wq : ((z == 1) ? Wk : Wv);
    u16* out = wt + (size_t)z * HD * HD;
    int k0 = blockIdx.x * 64, n0 = blockIdx.y * 64;
    int t = threadIdx.x;
    int r = t >> 4, c4 = (t & 15) * 4;
    for (int h = 0; h < 4; ++h) {
        int row = r + h * 16;
        floatx4 v = *(const floatx4*)(W + (size_t)(k0 + row) * HD + n0 + c4);
        tile[row * 65 + c4 + 0] = f2bf(v[0]);
        tile[row * 65 + c4 + 1] = f2bf(v[1]);
        tile[row * 65 + c4 + 2] = f2bf(v[2]);
        tile[row * 65 + c4 + 3] = f2bf(v[3]);
    }
    __syncthreads();
    int r2 = t >> 3, c8 = (t & 7) * 8;
    union { short8 v; u16 u[8]; } buf;
    for (int h = 0; h < 2; ++h) {
        int rr = r2 + h * 32;
        #pragma unroll
        for (int i = 0; i < 8; ++i) buf.u[i] = tile[(c8 + i) * 65 + rr];
        *(short8*)(out + (size_t)(n0 + rr) * HD + k0 + c8) = buf.v;
    }
}

// ---------------- Kernel 1: QKV GEMM (bf16 in, f32 bias, bf16 out) ----------------
// m97 structure: 128x128 tile, BK=32, global_load_lds width-16 staging into
// LINEAR LDS [128][32], with both-sides XOR swizzle (slot ^= (row>>1)&3):
//   - global SOURCE column-slot is pre-swizzled (per-lane address),
//   - LDS dest stays linear (global_load_lds requirement, m104/m108),
//   - fragment ds_read_b128 applies the same involution on its slot.
// This spreads each 16-lane fragment read across all 8 16B bank granules
// (linear layout would serialize 4-8-way; +1 padding is impossible here).
__global__ __launch_bounds__(256, 2) void qkv_gemm(const u16* __restrict__ x,
                                                   const u16* __restrict__ wt,
                                                   const float* __restrict__ bq,
                                                   const float* __restrict__ bk,
                                                   const float* __restrict__ bv,
                                                   u16* __restrict__ qb,
                                                   u16* __restrict__ kbuf,
                                                   u16* __restrict__ vtb) {
    __shared__ __align__(16) u16 sA[128 * 32];
    __shared__ __align__(16) u16 sB[128 * 32];
    int z = blockIdx.z;
    const u16* Bt = wt + (size_t)z * HD * HD;
    const float* bias = (z == 0) ? bq : ((z == 1) ? bk : bv);
    int m0 = blockIdx.x * 128, n0 = blockIdx.y * 128;
    int t = threadIdx.x, lane = t & 63, w = t >> 6;
    int quad = lane >> 4, l16 = lane & 15;
    int wm = w >> 1, wn = w & 1;
    floatx4 acc[4][4] = {};

    // staging: wave w owns rows [w*32, w*32+32), two 16-row chunks of 1024B.
    // lane ln -> row = w*32 + c*16 + (ln>>2), lds slot = ln&3.
    // source col-slot = (ln&3) ^ ((row>>1)&3) = (ln&3) ^ ((ln>>3)&3)
    // (w*16 and c*8 contribute 0 mod 4 to (row>>1)).
    int srow = w * 32 + (lane >> 2);
    int sswz = (lane & 3) ^ ((lane >> 3) & 3);
    const u16* gA = x + (size_t)(m0 + srow) * HD + sswz * 8;
    const u16* gB = Bt + (size_t)(n0 + srow) * HD + sswz * 8;
    u16* lA0 = &sA[(w * 32) * 32];
    u16* lA1 = &sA[(w * 32 + 16) * 32];
    u16* lB0 = &sB[(w * 32) * 32];
    u16* lB1 = &sB[(w * 32 + 16) * 32];

    for (int k0 = 0; k0 < HD; k0 += 32) {
        __builtin_amdgcn_global_load_lds(
            (const __attribute__((address_space(1))) unsigned int*)(const void*)(gA + k0),
            (__attribute__((address_space(3))) unsigned int*)(void*)lA0, 16, 0, 0);
        __builtin_amdgcn_global_load_lds(
            (const __attribute__((address_space(1))) unsigned int*)(const void*)(gA + (size_t)16 * HD + k0),
            (__attribute__((address_space(3))) unsigned int*)(void*)lA1, 16, 0, 0);
        __builtin_amdgcn_global_load_lds(
            (const __attribute__((address_space(1))) unsigned int*)(const void*)(gB + k0),
            (__attribute__((address_space(3))) unsigned int*)(void*)lB0, 16, 0, 0);
        __builtin_amdgcn_global_load_lds(
            (const __attribute__((address_space(1))) unsigned int*)(const void*)(gB + (size_t)16 * HD + k0),
            (__attribute__((address_space(3))) unsigned int*)(void*)lB1, 16, 0, 0);
        __syncthreads();   // compiler emits vmcnt(0) drain before s_barrier
        short8 af[4], bfr[4];
        #pragma unroll
        for (int i = 0; i < 4; ++i) {
            int ra = wm * 64 + i * 16 + l16;
            af[i] = *(const short8*)&sA[ra * 32 + (quad ^ ((ra >> 1) & 3)) * 8];
        }
        #pragma unroll
        for (int j = 0; j < 4; ++j) {
            int rb = wn * 64 + j * 16 + l16;
            bfr[j] = *(const short8*)&sB[rb * 32 + (quad ^ ((rb >> 1) & 3)) * 8];
        }
        #pragma unroll
        for (int i = 0; i < 4; ++i)
            #pragma unroll
            for (int j = 0; j < 4; ++j)
                acc[i][j] = __builtin_amdgcn_mfma_f32_16x16x32_bf16(af[i], bfr[j], acc[i][j], 0, 0, 0);
        __syncthreads();   // protect sA/sB from next iteration's staging
    }

    #pragma unroll
    for (int j = 0; j < 4; ++j) {
        int n = n0 + wn * 64 + j * 16 + l16;
        float bb = bias[n];
        #pragma unroll
        for (int i = 0; i < 4; ++i) {
            #pragma unroll
            for (int rr = 0; rr < 4; ++rr) {
                int m = m0 + wm * 64 + i * 16 + quad * 4 + rr;
                u16 h = f2bf(acc[i][j][rr] + bb);
                if (z == 0) {
                    qb[(size_t)m * HD + n] = h;
                } else if (z == 1) {
                    kbuf[(size_t)m * HD + n] = h;
                } else {
                    int b = m >> 12, s = m & 4095;
                    vtb[((size_t)(b * HD + n)) * SEQ + s] = h;
                }
            }
        }
    }
}

// ---------------- Kernel 2: flash attention (bf16 in, f32 out) ----------------
// Mq=64/block, 512 threads (8 waves), grid 256 (1 block/CU, 2 waves/SIMD).
// Halves K/V re-read traffic vs Mq=32 (the L2/L3-path ceiling, ~8.6 TB/s).
// Phase 1: wave w -> kcol group j=w&3 (16 k-cols), hidden half hh=w>>2 (512 of
//   1024). Each wave loads a DISTINCT 16KB K chunk (no duplication) and
//   computes partial S[64x16]; halves combine in-place in Sc (write, barrier,
//   add, barrier).
// Phase 2: 512 lanes, 8 lanes/row, online softmax, P bf16 -> Pb.
// Phase 3: wave w owns d-slice w*128; o_acc 128 VGPRs; V loads line-optimal.
__global__ __launch_bounds__(512, 2) void flash_kernel(const u16* __restrict__ q,
                                                       const u16* __restrict__ k,
                                                       const u16* __restrict__ vt,
                                                       float* __restrict__ out) {
    __shared__ __align__(16) u16 q_lds[64 * 1032];  // 132096 B; stride 2064B -> 2-way banks (free)
    __shared__ float Sc[64 * 66];                    // 16896 B
    __shared__ __align__(16) u16 Pb[64 * 72];        // 9216 B; 144B row stride, 16B aligned
    __shared__ float m_st[64], l_st[64], al_st[64];  // 768 B   => total 158976 B

    int t = threadIdx.x, lane = t & 63, w = t >> 6;
    int quad = lane >> 4, l16 = lane & 15;
    int j = w & 3, hh = w >> 2;
    int bid = blockIdx.x;
    int xcd = bid & 7;
    int b = xcd >> 1;                          // 2 XCDs per batch
    int q0 = (((bid >> 3) << 1) + (xcd & 1)) * 64;  // 64 q-tiles per batch

    // stage Q tile [64 x 1024]
    for (int i = t; i < 64 * 128; i += 512) {
        int r = i >> 7, c8 = (i & 127) * 8;
        *(short8*)&q_lds[r * 1032 + c8] =
            *(const short8*)&q[((size_t)(b * SEQ + q0 + r)) * HD + c8];
    }
    if (t < 64) { m_st[t] = -1e30f; l_st[t] = 0.f; }
    floatx4 o_acc[4][8] = {};
    __syncthreads();

    const u16* kwave = k + ((size_t)(b * SEQ + j * 16 + l16)) * HD + hh * 512 + quad * 8;
    const u16* vwave = vt + ((size_t)(b * HD + w * 128 + l16)) * SEQ + quad * 8;
    int r2 = t >> 3;                // 64 rows, 8 lanes each
    int cg = (t & 7) * 8;           // 8 cols per lane

    for (int tt = 0; tt < 64; ++tt) {
        int kb = tt * 64;
        // ---- phase 1: partial S = Q_slice K_slice^T (16 k-cols, 512 h) ----
        // unroll 8: 8 K-loads in flight to cover L2/L3 latency at 2 waves/SIMD
        floatx4 s_acc[4] = {};
        const u16* kp = kwave + (size_t)kb * HD;
        #pragma unroll 8
        for (int ks = 0; ks < 16; ++ks) {
            short8 kf = *(const short8*)(kp + ks * 32);
            #pragma unroll
            for (int rb = 0; rb < 4; ++rb) {
                short8 qf = *(const short8*)&q_lds[(rb * 16 + l16) * 1032 + hh * 512 + ks * 32 + quad * 8];
                s_acc[rb] = __builtin_amdgcn_mfma_f32_16x16x32_bf16(qf, kf, s_acc[rb], 0, 0, 0);
            }
        }
        if (hh == 0) {
            #pragma unroll
            for (int rb = 0; rb < 4; ++rb)
                #pragma unroll
                for (int rr = 0; rr < 4; ++rr)
                    Sc[(rb * 16 + quad * 4 + rr) * 66 + j * 16 + l16] = s_acc[rb][rr] * 0.03125f;
        }
        __syncthreads();
        if (hh == 1) {
            #pragma unroll
            for (int rb = 0; rb < 4; ++rb)
                #pragma unroll
                for (int rr = 0; rr < 4; ++rr)
                    Sc[(rb * 16 + quad * 4 + rr) * 66 + j * 16 + l16] += s_acc[rb][rr] * 0.03125f;
        }
        __syncthreads();

        // ---- phase 2: online softmax (row r2, 8 cols per lane) ----
        float sv[8];
        float mloc = -1e30f;
        #pragma unroll
        for (int i = 0; i < 8; ++i) { sv[i] = Sc[r2 * 66 + cg + i]; mloc = fmaxf(mloc, sv[i]); }
        mloc = fmaxf(mloc, __shfl_xor(mloc, 1));
        mloc = fmaxf(mloc, __shfl_xor(mloc, 2));
        mloc = fmaxf(mloc, __shfl_xor(mloc, 4));
        float m_old = m_st[r2];
        float m_new = fmaxf(m_old, mloc);
        float alpha = __expf(m_old - m_new);
        float sum = 0.f;
        #pragma unroll
        for (int i = 0; i < 8; ++i) {
            float p = __expf(sv[i] - m_new);
            sum += p;
            Pb[r2 * 72 + cg + i] = f2bf(p);
        }
        sum += __shfl_xor(sum, 1);
        sum += __shfl_xor(sum, 2);
        sum += __shfl_xor(sum, 4);
        if ((t & 7) == 0) {
            m_st[r2] = m_new;
            l_st[r2] = l_st[r2] * alpha + sum;
            al_st[r2] = alpha;
        }
        __syncthreads();

        // ---- phase 3: O = O*alpha + P V (this wave's 128 d-cols) ----
        #pragma unroll
        for (int rb = 0; rb < 4; ++rb) {
            float a0 = al_st[rb * 16 + quad * 4 + 0];
            float a1 = al_st[rb * 16 + quad * 4 + 1];
            float a2 = al_st[rb * 16 + quad * 4 + 2];
            float a3 = al_st[rb * 16 + quad * 4 + 3];
            #pragma unroll
            for (int dt = 0; dt < 8; ++dt) {
                o_acc[rb][dt][0] *= a0;
                o_acc[rb][dt][1] *= a1;
                o_acc[rb][dt][2] *= a2;
                o_acc[rb][dt][3] *= a3;
            }
        }
        short8 pf[4][2];
        #pragma unroll
        for (int rb = 0; rb < 4; ++rb)
            #pragma unroll
            for (int ks2 = 0; ks2 < 2; ++ks2)
                pf[rb][ks2] = *(const short8*)&Pb[(rb * 16 + l16) * 72 + ks2 * 32 + quad * 8];
        const u16* vp = vwave + kb;
        #pragma unroll
        for (int dt = 0; dt < 8; ++dt) {
            short8 vf0 = *(const short8*)(vp + (size_t)dt * 16 * SEQ);
            short8 vf1 = *(const short8*)(vp + (size_t)dt * 16 * SEQ + 32);
            #pragma unroll
            for (int rb = 0; rb < 4; ++rb) {
                o_acc[rb][dt] = __builtin_amdgcn_mfma_f32_16x16x32_bf16(pf[rb][0], vf0, o_acc[rb][dt], 0, 0, 0);
                o_acc[rb][dt] = __builtin_amdgcn_mfma_f32_16x16x32_bf16(pf[rb][1], vf1, o_acc[rb][dt], 0, 0, 0);
            }
        }
        // next iteration's barriers order phase-3 reads of Pb/al_st against
        // the next phase-2 writes; phase 1 touches only Sc/q_lds.
    }

    // epilogue: O /= l, write f32
    #pragma unroll
    for (int rb = 0; rb < 4; ++rb) {
        #pragma unroll
        for (int rr = 0; rr < 4; ++rr) {
            int row = rb * 16 + quad * 4 + rr;
            float linv = 1.f / l_st[row];
            #pragma unroll
            for (int dt = 0; dt < 8; ++dt) {
                out[((size_t)(b * SEQ + q0 + row)) * HD + w * 128 + dt * 16 + l16] =
                    o_acc[rb][dt][rr] * linv;
            }
        }
    }
}

extern "C" void kernel_launch(void* const* d_in, const int* in_sizes, int n_in,
                              void* d_out, int out_size, void* d_ws, size_t ws_size,
                              hipStream_t stream) {
    const float* x  = (const float*)d_in[0];
    const float* Wq = (const float*)d_in[1];
    const float* bq = (const float*)d_in[2];
    const float* Wk = (const float*)d_in[3];
    const float* bk = (const float*)d_in[4];
    const float* Wv = (const float*)d_in[5];
    const float* bv = (const float*)d_in[6];
    float* out = (float*)d_out;

    char* ws = (char*)d_ws;
    u16* xb  = (u16*)ws;                                   // 32 MB (x as bf16)
    u16* wt  = (u16*)(ws + (size_t)32 * 1024 * 1024);      // 6 MB
    u16* qb  = (u16*)(ws + (size_t)38 * 1024 * 1024);      // 32 MB
    u16* kb  = (u16*)(ws + (size_t)70 * 1024 * 1024);      // 32 MB
    u16* vtb = (u16*)(ws + (size_t)102 * 1024 * 1024);     // 32 MB (V transposed per batch)

    cvt_kernel<<<dim3(4096), 256, 0, stream>>>(x, xb, (4 * SEQ * HD) / 4);
    wt_kernel<<<dim3(16, 16, 3), 256, 0, stream>>>(Wq, Wk, Wv, wt);
    qkv_gemm<<<dim3(128, 8, 3), 256, 0, stream>>>(xb, wt, bq, bk, bv, qb, kb, vtb);
    flash_kernel<<<dim3(256), 512, 0, stream>>>(qb, kb, vtb, out);
}

// Round 3
// 802.571 us; speedup vs baseline: 1.0199x; 1.0199x over previous
//
#include <hip/hip_runtime.h>

typedef unsigned short u16;
typedef __attribute__((ext_vector_type(8))) short short8;
typedef __attribute__((ext_vector_type(4))) short short4v;
typedef __attribute__((ext_vector_type(4))) float floatx4;

#define HD 1024
#define SEQ 4096

__device__ inline u16 f2bf(float f) {
    union { float f; unsigned int i; } c; c.f = f;
    unsigned int r = c.i + 0x7fffu + ((c.i >> 16) & 1u);
    return (u16)(r >> 16);
}

// ---------------- Kernel A: x f32 -> bf16 ----------------
__global__ __launch_bounds__(256) void cvt_kernel(const float* __restrict__ in,
                                                  u16* __restrict__ out, int n4) {
    int idx = blockIdx.x * 256 + threadIdx.x;
    int stride = gridDim.x * 256;
    for (int i = idx; i < n4; i += stride) {
        floatx4 v = ((const floatx4*)in)[i];
        short4v o;
        o[0] = (short)f2bf(v[0]); o[1] = (short)f2bf(v[1]);
        o[2] = (short)f2bf(v[2]); o[3] = (short)f2bf(v[3]);
        ((short4v*)out)[i] = o;
    }
}

// ---------------- Kernel 0: W f32 [k][n] -> Wt bf16 [n][k], 3 matrices ----------------
__global__ __launch_bounds__(256) void wt_kernel(const float* __restrict__ Wq,
                                                 const float* __restrict__ Wk,
                                                 const float* __restrict__ Wv,
                                                 u16* __restrict__ wt) {
    __shared__ u16 tile[64 * 65];
    int z = blockIdx.z;
    const float* W = (z == 0) ? Wq : ((z == 1) ? Wk : Wv);
    u16* out = wt + (size_t)z * HD * HD;
    int k0 = blockIdx.x * 64, n0 = blockIdx.y * 64;
    int t = threadIdx.x;
    int r = t >> 4, c4 = (t & 15) * 4;
    for (int h = 0; h < 4; ++h) {
        int row = r + h * 16;
        floatx4 v = *(const floatx4*)(W + (size_t)(k0 + row) * HD + n0 + c4);
        tile[row * 65 + c4 + 0] = f2bf(v[0]);
        tile[row * 65 + c4 + 1] = f2bf(v[1]);
        tile[row * 65 + c4 + 2] = f2bf(v[2]);
        tile[row * 65 + c4 + 3] = f2bf(v[3]);
    }
    __syncthreads();
    int r2 = t >> 3, c8 = (t & 7) * 8;
    union { short8 v; u16 u[8]; } buf;
    for (int h = 0; h < 2; ++h) {
        int rr = r2 + h * 32;
        #pragma unroll
        for (int i = 0; i < 8; ++i) buf.u[i] = tile[(c8 + i) * 65 + rr];
        *(short8*)(out + (size_t)(n0 + rr) * HD + k0 + c8) = buf.v;
    }
}

// ---------------- Kernel 1: QKV GEMM (bf16 in, f32 bias, bf16 out) ----------------
// m97 structure: 128x128 tile, BK=32, global_load_lds width-16 staging into
// LINEAR LDS [128][32] (validated correct in round 2; round-2's small absmax
// proves the staging/swizzle/epilogue math is right).
// Epilogue: LDS-bounce the 128x128 tile (bf16) so all three outputs
// (qb/kb row-major, vtb transposed [b][d][s]) write coalesced 16B runs
// instead of the z==2 scattered 2B stores. tileC stride 132 keeps LDS at
// 50KB -> 2 blocks/CU.
__global__ __launch_bounds__(256, 2) void qkv_gemm(const u16* __restrict__ x,
                                                   const u16* __restrict__ wt,
                                                   const float* __restrict__ bq,
                                                   const float* __restrict__ bk,
                                                   const float* __restrict__ bv,
                                                   u16* __restrict__ qb,
                                                   u16* __restrict__ kbuf,
                                                   u16* __restrict__ vtb) {
    __shared__ __align__(16) u16 sA[128 * 32];
    __shared__ __align__(16) u16 sB[128 * 32];
    __shared__ __align__(16) u16 tileC[128 * 132];
    int z = blockIdx.z;
    const u16* Bt = wt + (size_t)z * HD * HD;
    const float* bias = (z == 0) ? bq : ((z == 1) ? bk : bv);
    int m0 = blockIdx.x * 128, n0 = blockIdx.y * 128;
    int t = threadIdx.x, lane = t & 63, w = t >> 6;
    int quad = lane >> 4, l16 = lane & 15;
    int wm = w >> 1, wn = w & 1;
    floatx4 acc[4][4] = {};

    // staging: wave w owns rows [w*32, w*32+32), two 16-row chunks of 1024B.
    // lane ln -> row = w*32 + c*16 + (ln>>2), lds slot = ln&3.
    // source col-slot = (ln&3) ^ ((row>>1)&3) = (ln&3) ^ ((ln>>3)&3).
    int srow = w * 32 + (lane >> 2);
    int sswz = (lane & 3) ^ ((lane >> 3) & 3);
    const u16* gA = x + (size_t)(m0 + srow) * HD + sswz * 8;
    const u16* gB = Bt + (size_t)(n0 + srow) * HD + sswz * 8;
    u16* lA0 = &sA[(w * 32) * 32];
    u16* lA1 = &sA[(w * 32 + 16) * 32];
    u16* lB0 = &sB[(w * 32) * 32];
    u16* lB1 = &sB[(w * 32 + 16) * 32];

    for (int k0 = 0; k0 < HD; k0 += 32) {
        __builtin_amdgcn_global_load_lds(
            (const __attribute__((address_space(1))) unsigned int*)(const void*)(gA + k0),
            (__attribute__((address_space(3))) unsigned int*)(void*)lA0, 16, 0, 0);
        __builtin_amdgcn_global_load_lds(
            (const __attribute__((address_space(1))) unsigned int*)(const void*)(gA + (size_t)16 * HD + k0),
            (__attribute__((address_space(3))) unsigned int*)(void*)lA1, 16, 0, 0);
        __builtin_amdgcn_global_load_lds(
            (const __attribute__((address_space(1))) unsigned int*)(const void*)(gB + k0),
            (__attribute__((address_space(3))) unsigned int*)(void*)lB0, 16, 0, 0);
        __builtin_amdgcn_global_load_lds(
            (const __attribute__((address_space(1))) unsigned int*)(const void*)(gB + (size_t)16 * HD + k0),
            (__attribute__((address_space(3))) unsigned int*)(void*)lB1, 16, 0, 0);
        __syncthreads();
        short8 af[4], bfr[4];
        #pragma unroll
        for (int i = 0; i < 4; ++i) {
            int ra = wm * 64 + i * 16 + l16;
            af[i] = *(const short8*)&sA[ra * 32 + (quad ^ ((ra >> 1) & 3)) * 8];
        }
        #pragma unroll
        for (int j = 0; j < 4; ++j) {
            int rb = wn * 64 + j * 16 + l16;
            bfr[j] = *(const short8*)&sB[rb * 32 + (quad ^ ((rb >> 1) & 3)) * 8];
        }
        #pragma unroll
        for (int i = 0; i < 4; ++i)
            #pragma unroll
            for (int j = 0; j < 4; ++j)
                acc[i][j] = __builtin_amdgcn_mfma_f32_16x16x32_bf16(af[i], bfr[j], acc[i][j], 0, 0, 0);
        __syncthreads();
    }

    // epilogue: bias + bf16 into LDS tile, then coalesced global writes
    #pragma unroll
    for (int j = 0; j < 4; ++j) {
        int nl = wn * 64 + j * 16 + l16;
        float bb = bias[n0 + nl];
        #pragma unroll
        for (int i = 0; i < 4; ++i) {
            #pragma unroll
            for (int rr = 0; rr < 4; ++rr) {
                int ml = wm * 64 + i * 16 + quad * 4 + rr;
                tileC[ml * 132 + nl] = f2bf(acc[i][j][rr] + bb);
            }
        }
    }
    __syncthreads();
    int r = t >> 1, c0 = (t & 1) * 64;
    if (z != 2) {
        u16* dst = (z == 0) ? qb : kbuf;
        #pragma unroll
        for (int v = 0; v < 8; ++v) {
            short8 vv = *(const short8*)&tileC[r * 132 + c0 + v * 8];
            *(short8*)&dst[(size_t)(m0 + r) * HD + n0 + c0 + v * 8] = vv;
        }
    } else {
        int b_ = m0 >> 12, s0 = m0 & 4095;
        #pragma unroll
        for (int v = 0; v < 8; ++v) {
            union { short8 vv; u16 u[8]; } pk;
            #pragma unroll
            for (int e = 0; e < 8; ++e) pk.u[e] = tileC[(c0 + v * 8 + e) * 132 + r];
            *(short8*)&vtb[((size_t)(b_ * HD + n0 + r)) * SEQ + s0 + c0 + v * 8] = pk.vv;
        }
    }
}

// ---------------- Kernel 2: flash attention (bf16 in, f32 out) ----------------
// Byte-identical to the round-1 proven version (593us, absmax 1.95e-3).
// Mq=64/block, 512 threads (8 waves), grid 256 (1 block/CU).
// Counters say: 82% of the ~8.6 TB/s L2/L3 path; the 4.6e7 LDS "conflicts"
// are the inherent 8-cycle floor of 512 ds_read_b128/iter (1KB each), not
// fixable. fp8 byte-halving is numerically dead (round 2). Remaining lever
// is a pipeline restructure (separate round).
__global__ __launch_bounds__(512, 2) void flash_kernel(const u16* __restrict__ q,
                                                       const u16* __restrict__ k,
                                                       const u16* __restrict__ vt,
                                                       float* __restrict__ out) {
    __shared__ __align__(16) u16 q_lds[64 * 1032];  // 132096 B; stride 2064B -> 2-way banks (free)
    __shared__ float Sc[64 * 66];                    // 16896 B
    __shared__ __align__(16) u16 Pb[64 * 72];        // 9216 B
    __shared__ float m_st[64], l_st[64], al_st[64];  // 768 B   => total 158976 B

    int t = threadIdx.x, lane = t & 63, w = t >> 6;
    int quad = lane >> 4, l16 = lane & 15;
    int j = w & 3, hh = w >> 2;
    int bid = blockIdx.x;
    int xcd = bid & 7;
    int b = xcd >> 1;                          // 2 XCDs per batch
    int q0 = (((bid >> 3) << 1) + (xcd & 1)) * 64;  // 64 q-tiles per batch

    // stage Q tile [64 x 1024]
    for (int i = t; i < 64 * 128; i += 512) {
        int r = i >> 7, c8 = (i & 127) * 8;
        *(short8*)&q_lds[r * 1032 + c8] =
            *(const short8*)&q[((size_t)(b * SEQ + q0 + r)) * HD + c8];
    }
    if (t < 64) { m_st[t] = -1e30f; l_st[t] = 0.f; }
    floatx4 o_acc[4][8] = {};
    __syncthreads();

    const u16* kwave = k + ((size_t)(b * SEQ + j * 16 + l16)) * HD + hh * 512 + quad * 8;
    const u16* vwave = vt + ((size_t)(b * HD + w * 128 + l16)) * SEQ + quad * 8;
    int r2 = t >> 3;                // 64 rows, 8 lanes each
    int cg = (t & 7) * 8;           // 8 cols per lane

    for (int tt = 0; tt < 64; ++tt) {
        int kb = tt * 64;
        // ---- phase 1: partial S = Q_slice K_slice^T (16 k-cols, 512 h) ----
        floatx4 s_acc[4] = {};
        const u16* kp = kwave + (size_t)kb * HD;
        #pragma unroll 8
        for (int ks = 0; ks < 16; ++ks) {
            short8 kf = *(const short8*)(kp + ks * 32);
            #pragma unroll
            for (int rb = 0; rb < 4; ++rb) {
                short8 qf = *(const short8*)&q_lds[(rb * 16 + l16) * 1032 + hh * 512 + ks * 32 + quad * 8];
                s_acc[rb] = __builtin_amdgcn_mfma_f32_16x16x32_bf16(qf, kf, s_acc[rb], 0, 0, 0);
            }
        }
        if (hh == 0) {
            #pragma unroll
            for (int rb = 0; rb < 4; ++rb)
                #pragma unroll
                for (int rr = 0; rr < 4; ++rr)
                    Sc[(rb * 16 + quad * 4 + rr) * 66 + j * 16 + l16] = s_acc[rb][rr] * 0.03125f;
        }
        __syncthreads();
        if (hh == 1) {
            #pragma unroll
            for (int rb = 0; rb < 4; ++rb)
                #pragma unroll
                for (int rr = 0; rr < 4; ++rr)
                    Sc[(rb * 16 + quad * 4 + rr) * 66 + j * 16 + l16] += s_acc[rb][rr] * 0.03125f;
        }
        __syncthreads();

        // ---- phase 2: online softmax (row r2, 8 cols per lane) ----
        float sv[8];
        float mloc = -1e30f;
        #pragma unroll
        for (int i = 0; i < 8; ++i) { sv[i] = Sc[r2 * 66 + cg + i]; mloc = fmaxf(mloc, sv[i]); }
        mloc = fmaxf(mloc, __shfl_xor(mloc, 1));
        mloc = fmaxf(mloc, __shfl_xor(mloc, 2));
        mloc = fmaxf(mloc, __shfl_xor(mloc, 4));
        float m_old = m_st[r2];
        float m_new = fmaxf(m_old, mloc);
        float alpha = __expf(m_old - m_new);
        float sum = 0.f;
        #pragma unroll
        for (int i = 0; i < 8; ++i) {
            float p = __expf(sv[i] - m_new);
            sum += p;
            Pb[r2 * 72 + cg + i] = f2bf(p);
        }
        sum += __shfl_xor(sum, 1);
        sum += __shfl_xor(sum, 2);
        sum += __shfl_xor(sum, 4);
        if ((t & 7) == 0) {
            m_st[r2] = m_new;
            l_st[r2] = l_st[r2] * alpha + sum;
            al_st[r2] = alpha;
        }
        __syncthreads();

        // ---- phase 3: O = O*alpha + P V (this wave's 128 d-cols) ----
        #pragma unroll
        for (int rb = 0; rb < 4; ++rb) {
            float a0 = al_st[rb * 16 + quad * 4 + 0];
            float a1 = al_st[rb * 16 + quad * 4 + 1];
            float a2 = al_st[rb * 16 + quad * 4 + 2];
            float a3 = al_st[rb * 16 + quad * 4 + 3];
            #pragma unroll
            for (int dt = 0; dt < 8; ++dt) {
                o_acc[rb][dt][0] *= a0;
                o_acc[rb][dt][1] *= a1;
                o_acc[rb][dt][2] *= a2;
                o_acc[rb][dt][3] *= a3;
            }
        }
        short8 pf[4][2];
        #pragma unroll
        for (int rb = 0; rb < 4; ++rb)
            #pragma unroll
            for (int ks2 = 0; ks2 < 2; ++ks2)
                pf[rb][ks2] = *(const short8*)&Pb[(rb * 16 + l16) * 72 + ks2 * 32 + quad * 8];
        const u16* vp = vwave + kb;
        #pragma unroll
        for (int dt = 0; dt < 8; ++dt) {
            short8 vf0 = *(const short8*)(vp + (size_t)dt * 16 * SEQ);
            short8 vf1 = *(const short8*)(vp + (size_t)dt * 16 * SEQ + 32);
            #pragma unroll
            for (int rb = 0; rb < 4; ++rb) {
                o_acc[rb][dt] = __builtin_amdgcn_mfma_f32_16x16x32_bf16(pf[rb][0], vf0, o_acc[rb][dt], 0, 0, 0);
                o_acc[rb][dt] = __builtin_amdgcn_mfma_f32_16x16x32_bf16(pf[rb][1], vf1, o_acc[rb][dt], 0, 0, 0);
            }
        }
        // next iteration's barriers order phase-3 reads of Pb/al_st against
        // the next phase-2 writes; phase 1 touches only Sc/q_lds.
    }

    // epilogue: O /= l, write f32
    #pragma unroll
    for (int rb = 0; rb < 4; ++rb) {
        #pragma unroll
        for (int rr = 0; rr < 4; ++rr) {
            int row = rb * 16 + quad * 4 + rr;
            float linv = 1.f / l_st[row];
            #pragma unroll
            for (int dt = 0; dt < 8; ++dt) {
                out[((size_t)(b * SEQ + q0 + row)) * HD + w * 128 + dt * 16 + l16] =
                    o_acc[rb][dt][rr] * linv;
            }
        }
    }
}

extern "C" void kernel_launch(void* const* d_in, const int* in_sizes, int n_in,
                              void* d_out, int out_size, void* d_ws, size_t ws_size,
                              hipStream_t stream) {
    const float* x  = (const float*)d_in[0];
    const float* Wq = (const float*)d_in[1];
    const float* bq = (const float*)d_in[2];
    const float* Wk = (const float*)d_in[3];
    const float* bk = (const float*)d_in[4];
    const float* Wv = (const float*)d_in[5];
    const float* bv = (const float*)d_in[6];
    float* out = (float*)d_out;

    char* ws = (char*)d_ws;
    u16* xb  = (u16*)ws;                                   // 32 MB (x as bf16)
    u16* wt  = (u16*)(ws + (size_t)32 * 1024 * 1024);      // 6 MB
    u16* qb  = (u16*)(ws + (size_t)38 * 1024 * 1024);      // 32 MB
    u16* kb  = (u16*)(ws + (size_t)70 * 1024 * 1024);      // 32 MB
    u16* vtb = (u16*)(ws + (size_t)102 * 1024 * 1024);     // 32 MB (V transposed per batch)

    cvt_kernel<<<dim3(4096), 256, 0, stream>>>(x, xb, (4 * SEQ * HD) / 4);
    wt_kernel<<<dim3(16, 16, 3), 256, 0, stream>>>(Wq, Wk, Wv, wt);
    qkv_gemm<<<dim3(128, 8, 3), 256, 0, stream>>>(xb, wt, bq, bk, bv, qb, kb, vtb);
    flash_kernel<<<dim3(256), 512, 0, stream>>>(qb, kb, vtb, out);
}

// Round 4
// 623.211 us; speedup vs baseline: 1.3134x; 1.2878x over previous
//
#include <hip/hip_runtime.h>

typedef unsigned short u16;
typedef __attribute__((ext_vector_type(8))) short short8;
typedef __attribute__((ext_vector_type(4))) short short4v;
typedef __attribute__((ext_vector_type(4))) float floatx4;

#define HD 1024
#define SEQ 4096

__device__ inline u16 f2bf(float f) {
    union { float f; unsigned int i; } c; c.f = f;
    unsigned int r = c.i + 0x7fffu + ((c.i >> 16) & 1u);
    return (u16)(r >> 16);
}

__device__ inline float bf2f(u16 h) {
    union { unsigned int u; float f; } c; c.u = ((unsigned int)h) << 16;
    return c.f;
}

// bijective XCD-chunk swizzle (m204): nwg % 8 == 0 required.
// Groups of nwg/8 consecutive logical ids land on one XCD.
__device__ inline int xcd_chunk(int bid, int nwg) {
    int q = nwg >> 3;
    return (bid & 7) * q + (bid >> 3);
}

// ---------------- Kernel A: x f32 -> bf16 ----------------
__global__ __launch_bounds__(256) void cvt_kernel(const float* __restrict__ in,
                                                  u16* __restrict__ out, int n4) {
    int idx = blockIdx.x * 256 + threadIdx.x;
    int stride = gridDim.x * 256;
    for (int i = idx; i < n4; i += stride) {
        floatx4 v = ((const floatx4*)in)[i];
        short4v o;
        o[0] = (short)f2bf(v[0]); o[1] = (short)f2bf(v[1]);
        o[2] = (short)f2bf(v[2]); o[3] = (short)f2bf(v[3]);
        ((short4v*)out)[i] = o;
    }
}

// ---------------- Kernel 0: W f32 [k][n] -> Wt bf16 [n][k], 3 matrices ----------------
__global__ __launch_bounds__(256) void wt_kernel(const float* __restrict__ Wq,
                                                 const float* __restrict__ Wk,
                                                 const float* __restrict__ Wv,
                                                 u16* __restrict__ wt) {
    __shared__ u16 tile[64 * 65];
    int z = blockIdx.z;
    const float* W = (z == 0) ? Wq : ((z == 1) ? Wk : Wv);
    u16* out = wt + (size_t)z * HD * HD;
    int k0 = blockIdx.x * 64, n0 = blockIdx.y * 64;
    int t = threadIdx.x;
    int r = t >> 4, c4 = (t & 15) * 4;
    for (int h = 0; h < 4; ++h) {
        int row = r + h * 16;
        floatx4 v = *(const floatx4*)(W + (size_t)(k0 + row) * HD + n0 + c4);
        tile[row * 65 + c4 + 0] = f2bf(v[0]);
        tile[row * 65 + c4 + 1] = f2bf(v[1]);
        tile[row * 65 + c4 + 2] = f2bf(v[2]);
        tile[row * 65 + c4 + 3] = f2bf(v[3]);
    }
    __syncthreads();
    int r2 = t >> 3, c8 = (t & 7) * 8;
    union { short8 v; u16 u[8]; } buf;
    for (int h = 0; h < 2; ++h) {
        int rr = r2 + h * 32;
        #pragma unroll
        for (int i = 0; i < 8; ++i) buf.u[i] = tile[(c8 + i) * 65 + rr];
        *(short8*)(out + (size_t)(n0 + rr) * HD + k0 + c8) = buf.v;
    }
}

// ---------------- Kernel 1: QKV GEMM (bf16 in, f32 bias, bf16 out) ----------------
// Validated 128x128 / BK=32 / global_load_lds structure (round 2/3).
__global__ __launch_bounds__(256, 2) void qkv_gemm(const u16* __restrict__ x,
                                                   const u16* __restrict__ wt,
                                                   const float* __restrict__ bq,
                                                   const float* __restrict__ bk,
                                                   const float* __restrict__ bv,
                                                   u16* __restrict__ qb,
                                                   u16* __restrict__ kbuf,
                                                   u16* __restrict__ vtb) {
    __shared__ __align__(16) u16 sA[128 * 32];
    __shared__ __align__(16) u16 sB[128 * 32];
    __shared__ __align__(16) u16 tileC[128 * 132];
    int z = blockIdx.z;
    const u16* Bt = wt + (size_t)z * HD * HD;
    const float* bias = (z == 0) ? bq : ((z == 1) ? bk : bv);
    int m0 = blockIdx.x * 128, n0 = blockIdx.y * 128;
    int t = threadIdx.x, lane = t & 63, w = t >> 6;
    int quad = lane >> 4, l16 = lane & 15;
    int wm = w >> 1, wn = w & 1;
    floatx4 acc[4][4] = {};

    int srow = w * 32 + (lane >> 2);
    int sswz = (lane & 3) ^ ((lane >> 3) & 3);
    const u16* gA = x + (size_t)(m0 + srow) * HD + sswz * 8;
    const u16* gB = Bt + (size_t)(n0 + srow) * HD + sswz * 8;
    u16* lA0 = &sA[(w * 32) * 32];
    u16* lA1 = &sA[(w * 32 + 16) * 32];
    u16* lB0 = &sB[(w * 32) * 32];
    u16* lB1 = &sB[(w * 32 + 16) * 32];

    for (int k0 = 0; k0 < HD; k0 += 32) {
        __builtin_amdgcn_global_load_lds(
            (const __attribute__((address_space(1))) unsigned int*)(const void*)(gA + k0),
            (__attribute__((address_space(3))) unsigned int*)(void*)lA0, 16, 0, 0);
        __builtin_amdgcn_global_load_lds(
            (const __attribute__((address_space(1))) unsigned int*)(const void*)(gA + (size_t)16 * HD + k0),
            (__attribute__((address_space(3))) unsigned int*)(void*)lA1, 16, 0, 0);
        __builtin_amdgcn_global_load_lds(
            (const __attribute__((address_space(1))) unsigned int*)(const void*)(gB + k0),
            (__attribute__((address_space(3))) unsigned int*)(void*)lB0, 16, 0, 0);
        __builtin_amdgcn_global_load_lds(
            (const __attribute__((address_space(1))) unsigned int*)(const void*)(gB + (size_t)16 * HD + k0),
            (__attribute__((address_space(3))) unsigned int*)(void*)lB1, 16, 0, 0);
        __syncthreads();
        short8 af[4], bfr[4];
        #pragma unroll
        for (int i = 0; i < 4; ++i) {
            int ra = wm * 64 + i * 16 + l16;
            af[i] = *(const short8*)&sA[ra * 32 + (quad ^ ((ra >> 1) & 3)) * 8];
        }
        #pragma unroll
        for (int j = 0; j < 4; ++j) {
            int rb = wn * 64 + j * 16 + l16;
            bfr[j] = *(const short8*)&sB[rb * 32 + (quad ^ ((rb >> 1) & 3)) * 8];
        }
        #pragma unroll
        for (int i = 0; i < 4; ++i)
            #pragma unroll
            for (int j = 0; j < 4; ++j)
                acc[i][j] = __builtin_amdgcn_mfma_f32_16x16x32_bf16(af[i], bfr[j], acc[i][j], 0, 0, 0);
        __syncthreads();
    }

    #pragma unroll
    for (int j = 0; j < 4; ++j) {
        int nl = wn * 64 + j * 16 + l16;
        float bb = bias[n0 + nl];
        #pragma unroll
        for (int i = 0; i < 4; ++i) {
            #pragma unroll
            for (int rr = 0; rr < 4; ++rr) {
                int ml = wm * 64 + i * 16 + quad * 4 + rr;
                tileC[ml * 132 + nl] = f2bf(acc[i][j][rr] + bb);
            }
        }
    }
    __syncthreads();
    int r = t >> 1, c0 = (t & 1) * 64;
    if (z != 2) {
        u16* dst = (z == 0) ? qb : kbuf;
        #pragma unroll
        for (int v = 0; v < 8; ++v) {
            short8 vv = *(const short8*)&tileC[r * 132 + c0 + v * 8];
            *(short8*)&dst[(size_t)(m0 + r) * HD + n0 + c0 + v * 8] = vv;
        }
    } else {
        int b_ = m0 >> 12, s0 = m0 & 4095;
        #pragma unroll
        for (int v = 0; v < 8; ++v) {
            union { short8 vv; u16 u[8]; } pk;
            #pragma unroll
            for (int e = 0; e < 8; ++e) pk.u[e] = tileC[(c0 + v * 8 + e) * 132 + r];
            *(short8*)&vtb[((size_t)(b_ * HD + n0 + r)) * SEQ + s0 + c0 + v * 8] = pk.vv;
        }
    }
}

// ---------------- Kernel S: S = Q K^T / 32  (bf16 out, per batch) ----------------
// Same validated structure as qkv_gemm. M=N=4096, K=1024. A=qb rows, Bt=kb rows.
// 1-D grid 4096 with XCD-chunk swizzle; logical id: n fastest (A-panel shared
// by consecutive ids, which stay on one XCD after the swizzle).
__global__ __launch_bounds__(256, 2) void gemm_s(const u16* __restrict__ qb,
                                                 const u16* __restrict__ kb,
                                                 u16* __restrict__ S) {
    __shared__ __align__(16) u16 sA[128 * 32];
    __shared__ __align__(16) u16 sB[128 * 32];
    __shared__ __align__(16) u16 tileC[128 * 132];
    int wg = xcd_chunk(blockIdx.x, 4096);
    int b = wg >> 10;
    int r10 = wg & 1023;
    int m0 = (r10 >> 5) * 128, n0 = (r10 & 31) * 128;
    const u16* A = qb + (size_t)b * SEQ * HD;
    const u16* Bt = kb + (size_t)b * SEQ * HD;
    int t = threadIdx.x, lane = t & 63, w = t >> 6;
    int quad = lane >> 4, l16 = lane & 15;
    int wm = w >> 1, wn = w & 1;
    floatx4 acc[4][4] = {};

    int srow = w * 32 + (lane >> 2);
    int sswz = (lane & 3) ^ ((lane >> 3) & 3);
    const u16* gA = A + (size_t)(m0 + srow) * HD + sswz * 8;
    const u16* gB = Bt + (size_t)(n0 + srow) * HD + sswz * 8;
    u16* lA0 = &sA[(w * 32) * 32];
    u16* lA1 = &sA[(w * 32 + 16) * 32];
    u16* lB0 = &sB[(w * 32) * 32];
    u16* lB1 = &sB[(w * 32 + 16) * 32];

    for (int k0 = 0; k0 < HD; k0 += 32) {
        __builtin_amdgcn_global_load_lds(
            (const __attribute__((address_space(1))) unsigned int*)(const void*)(gA + k0),
            (__attribute__((address_space(3))) unsigned int*)(void*)lA0, 16, 0, 0);
        __builtin_amdgcn_global_load_lds(
            (const __attribute__((address_space(1))) unsigned int*)(const void*)(gA + (size_t)16 * HD + k0),
            (__attribute__((address_space(3))) unsigned int*)(void*)lA1, 16, 0, 0);
        __builtin_amdgcn_global_load_lds(
            (const __attribute__((address_space(1))) unsigned int*)(const void*)(gB + k0),
            (__attribute__((address_space(3))) unsigned int*)(void*)lB0, 16, 0, 0);
        __builtin_amdgcn_global_load_lds(
            (const __attribute__((address_space(1))) unsigned int*)(const void*)(gB + (size_t)16 * HD + k0),
            (__attribute__((address_space(3))) unsigned int*)(void*)lB1, 16, 0, 0);
        __syncthreads();
        short8 af[4], bfr[4];
        #pragma unroll
        for (int i = 0; i < 4; ++i) {
            int ra = wm * 64 + i * 16 + l16;
            af[i] = *(const short8*)&sA[ra * 32 + (quad ^ ((ra >> 1) & 3)) * 8];
        }
        #pragma unroll
        for (int j = 0; j < 4; ++j) {
            int rb = wn * 64 + j * 16 + l16;
            bfr[j] = *(const short8*)&sB[rb * 32 + (quad ^ ((rb >> 1) & 3)) * 8];
        }
        #pragma unroll
        for (int i = 0; i < 4; ++i)
            #pragma unroll
            for (int j = 0; j < 4; ++j)
                acc[i][j] = __builtin_amdgcn_mfma_f32_16x16x32_bf16(af[i], bfr[j], acc[i][j], 0, 0, 0);
        __syncthreads();
    }

    #pragma unroll
    for (int j = 0; j < 4; ++j) {
        int nl = wn * 64 + j * 16 + l16;
        #pragma unroll
        for (int i = 0; i < 4; ++i) {
            #pragma unroll
            for (int rr = 0; rr < 4; ++rr) {
                int ml = wm * 64 + i * 16 + quad * 4 + rr;
                tileC[ml * 132 + nl] = f2bf(acc[i][j][rr] * 0.03125f);
            }
        }
    }
    __syncthreads();
    int r = t >> 1, c0 = (t & 1) * 64;
    #pragma unroll
    for (int v = 0; v < 8; ++v) {
        short8 vv = *(const short8*)&tileC[r * 132 + c0 + v * 8];
        *(short8*)&S[((size_t)b * SEQ + m0 + r) * SEQ + n0 + c0 + v * 8] = vv;
    }
}

// ---------------- Kernel SM: in-place row softmax on S (bf16) ----------------
// One wave per row (4096 elems = 64 f32/lane in registers). Writes P = exp/l.
__global__ __launch_bounds__(256) void softmax_kernel(u16* __restrict__ S) {
    int w = threadIdx.x >> 6, lane = threadIdx.x & 63;
    size_t row = (size_t)blockIdx.x * 4 + w;
    u16* p = S + row * SEQ;
    float sv[64];
    float mx = -1e30f;
    #pragma unroll
    for (int c = 0; c < 8; ++c) {
        short8 v = *(const short8*)&p[(c * 64 + lane) * 8];
        #pragma unroll
        for (int e = 0; e < 8; ++e) {
            float f = bf2f((u16)v[e]);
            sv[c * 8 + e] = f;
            mx = fmaxf(mx, f);
        }
    }
    mx = fmaxf(mx, __shfl_xor(mx, 1));
    mx = fmaxf(mx, __shfl_xor(mx, 2));
    mx = fmaxf(mx, __shfl_xor(mx, 4));
    mx = fmaxf(mx, __shfl_xor(mx, 8));
    mx = fmaxf(mx, __shfl_xor(mx, 16));
    mx = fmaxf(mx, __shfl_xor(mx, 32));
    float sum = 0.f;
    #pragma unroll
    for (int i = 0; i < 64; ++i) { sv[i] = __expf(sv[i] - mx); sum += sv[i]; }
    sum += __shfl_xor(sum, 1);
    sum += __shfl_xor(sum, 2);
    sum += __shfl_xor(sum, 4);
    sum += __shfl_xor(sum, 8);
    sum += __shfl_xor(sum, 16);
    sum += __shfl_xor(sum, 32);
    float rinv = 1.f / sum;
    #pragma unroll
    for (int c = 0; c < 8; ++c) {
        union { short8 vv; u16 u[8]; } o;
        #pragma unroll
        for (int e = 0; e < 8; ++e) o.u[e] = f2bf(sv[c * 8 + e] * rinv);
        *(short8*)&p[(c * 64 + lane) * 8] = o.vv;
    }
}

// ---------------- Kernel O: O = P V  (f32 out, per batch) ----------------
// A = P rows (lda=SEQ), Bt = vtb rows [b][d][s] (ldb=SEQ), K=4096.
// M=4096, N=1024. 1-D grid 1024 with XCD-chunk swizzle, n fastest.
__global__ __launch_bounds__(256, 2) void gemm_o(const u16* __restrict__ P,
                                                 const u16* __restrict__ vt,
                                                 float* __restrict__ out) {
    __shared__ __align__(16) u16 sA[128 * 32];
    __shared__ __align__(16) u16 sB[128 * 32];
    int wg = xcd_chunk(blockIdx.x, 1024);
    int b = wg >> 8;
    int r8 = wg & 255;
    int m0 = (r8 >> 3) * 128, n0 = (r8 & 7) * 128;
    const u16* A = P + (size_t)b * SEQ * SEQ;
    const u16* Bt = vt + (size_t)b * HD * SEQ;
    int t = threadIdx.x, lane = t & 63, w = t >> 6;
    int quad = lane >> 4, l16 = lane & 15;
    int wm = w >> 1, wn = w & 1;
    floatx4 acc[4][4] = {};

    int srow = w * 32 + (lane >> 2);
    int sswz = (lane & 3) ^ ((lane >> 3) & 3);
    const u16* gA = A + (size_t)(m0 + srow) * SEQ + sswz * 8;
    const u16* gB = Bt + (size_t)(n0 + srow) * SEQ + sswz * 8;
    u16* lA0 = &sA[(w * 32) * 32];
    u16* lA1 = &sA[(w * 32 + 16) * 32];
    u16* lB0 = &sB[(w * 32) * 32];
    u16* lB1 = &sB[(w * 32 + 16) * 32];

    for (int k0 = 0; k0 < SEQ; k0 += 32) {
        __builtin_amdgcn_global_load_lds(
            (const __attribute__((address_space(1))) unsigned int*)(const void*)(gA + k0),
            (__attribute__((address_space(3))) unsigned int*)(void*)lA0, 16, 0, 0);
        __builtin_amdgcn_global_load_lds(
            (const __attribute__((address_space(1))) unsigned int*)(const void*)(gA + (size_t)16 * SEQ + k0),
            (__attribute__((address_space(3))) unsigned int*)(void*)lA1, 16, 0, 0);
        __builtin_amdgcn_global_load_lds(
            (const __attribute__((address_space(1))) unsigned int*)(const void*)(gB + k0),
            (__attribute__((address_space(3))) unsigned int*)(void*)lB0, 16, 0, 0);
        __builtin_amdgcn_global_load_lds(
            (const __attribute__((address_space(1))) unsigned int*)(const void*)(gB + (size_t)16 * SEQ + k0),
            (__attribute__((address_space(3))) unsigned int*)(void*)lB1, 16, 0, 0);
        __syncthreads();
        short8 af[4], bfr[4];
        #pragma unroll
        for (int i = 0; i < 4; ++i) {
            int ra = wm * 64 + i * 16 + l16;
            af[i] = *(const short8*)&sA[ra * 32 + (quad ^ ((ra >> 1) & 3)) * 8];
        }
        #pragma unroll
        for (int j = 0; j < 4; ++j) {
            int rb = wn * 64 + j * 16 + l16;
            bfr[j] = *(const short8*)&sB[rb * 32 + (quad ^ ((rb >> 1) & 3)) * 8];
        }
        #pragma unroll
        for (int i = 0; i < 4; ++i)
            #pragma unroll
            for (int j = 0; j < 4; ++j)
                acc[i][j] = __builtin_amdgcn_mfma_f32_16x16x32_bf16(af[i], bfr[j], acc[i][j], 0, 0, 0);
        __syncthreads();
    }

    #pragma unroll
    for (int j = 0; j < 4; ++j) {
        int n = n0 + wn * 64 + j * 16 + l16;
        #pragma unroll
        for (int i = 0; i < 4; ++i) {
            #pragma unroll
            for (int rr = 0; rr < 4; ++rr) {
                int m = m0 + wm * 64 + i * 16 + quad * 4 + rr;
                out[((size_t)(b * SEQ + m)) * HD + n] = acc[i][j][rr];
            }
        }
    }
}

// ---------------- Fallback: flash attention (proven, 590us) ----------------
__global__ __launch_bounds__(512, 2) void flash_kernel(const u16* __restrict__ q,
                                                       const u16* __restrict__ k,
                                                       const u16* __restrict__ vt,
                                                       float* __restrict__ out) {
    __shared__ __align__(16) u16 q_lds[64 * 1032];
    __shared__ float Sc[64 * 66];
    __shared__ __align__(16) u16 Pb[64 * 72];
    __shared__ float m_st[64], l_st[64], al_st[64];

    int t = threadIdx.x, lane = t & 63, w = t >> 6;
    int quad = lane >> 4, l16 = lane & 15;
    int j = w & 3, hh = w >> 2;
    int bid = blockIdx.x;
    int xcd = bid & 7;
    int b = xcd >> 1;
    int q0 = (((bid >> 3) << 1) + (xcd & 1)) * 64;

    for (int i = t; i < 64 * 128; i += 512) {
        int r = i >> 7, c8 = (i & 127) * 8;
        *(short8*)&q_lds[r * 1032 + c8] =
            *(const short8*)&q[((size_t)(b * SEQ + q0 + r)) * HD + c8];
    }
    if (t < 64) { m_st[t] = -1e30f; l_st[t] = 0.f; }
    floatx4 o_acc[4][8] = {};
    __syncthreads();

    const u16* kwave = k + ((size_t)(b * SEQ + j * 16 + l16)) * HD + hh * 512 + quad * 8;
    const u16* vwave = vt + ((size_t)(b * HD + w * 128 + l16)) * SEQ + quad * 8;
    int r2 = t >> 3;
    int cg = (t & 7) * 8;

    for (int tt = 0; tt < 64; ++tt) {
        int kb = tt * 64;
        floatx4 s_acc[4] = {};
        const u16* kp = kwave + (size_t)kb * HD;
        #pragma unroll 8
        for (int ks = 0; ks < 16; ++ks) {
            short8 kf = *(const short8*)(kp + ks * 32);
            #pragma unroll
            for (int rb = 0; rb < 4; ++rb) {
                short8 qf = *(const short8*)&q_lds[(rb * 16 + l16) * 1032 + hh * 512 + ks * 32 + quad * 8];
                s_acc[rb] = __builtin_amdgcn_mfma_f32_16x16x32_bf16(qf, kf, s_acc[rb], 0, 0, 0);
            }
        }
        if (hh == 0) {
            #pragma unroll
            for (int rb = 0; rb < 4; ++rb)
                #pragma unroll
                for (int rr = 0; rr < 4; ++rr)
                    Sc[(rb * 16 + quad * 4 + rr) * 66 + j * 16 + l16] = s_acc[rb][rr] * 0.03125f;
        }
        __syncthreads();
        if (hh == 1) {
            #pragma unroll
            for (int rb = 0; rb < 4; ++rb)
                #pragma unroll
                for (int rr = 0; rr < 4; ++rr)
                    Sc[(rb * 16 + quad * 4 + rr) * 66 + j * 16 + l16] += s_acc[rb][rr] * 0.03125f;
        }
        __syncthreads();

        float sv[8];
        float mloc = -1e30f;
        #pragma unroll
        for (int i = 0; i < 8; ++i) { sv[i] = Sc[r2 * 66 + cg + i]; mloc = fmaxf(mloc, sv[i]); }
        mloc = fmaxf(mloc, __shfl_xor(mloc, 1));
        mloc = fmaxf(mloc, __shfl_xor(mloc, 2));
        mloc = fmaxf(mloc, __shfl_xor(mloc, 4));
        float m_old = m_st[r2];
        float m_new = fmaxf(m_old, mloc);
        float alpha = __expf(m_old - m_new);
        float sum = 0.f;
        #pragma unroll
        for (int i = 0; i < 8; ++i) {
            float p = __expf(sv[i] - m_new);
            sum += p;
            Pb[r2 * 72 + cg + i] = f2bf(p);
        }
        sum += __shfl_xor(sum, 1);
        sum += __shfl_xor(sum, 2);
        sum += __shfl_xor(sum, 4);
        if ((t & 7) == 0) {
            m_st[r2] = m_new;
            l_st[r2] = l_st[r2] * alpha + sum;
            al_st[r2] = alpha;
        }
        __syncthreads();

        #pragma unroll
        for (int rb = 0; rb < 4; ++rb) {
            float a0 = al_st[rb * 16 + quad * 4 + 0];
            float a1 = al_st[rb * 16 + quad * 4 + 1];
            float a2 = al_st[rb * 16 + quad * 4 + 2];
            float a3 = al_st[rb * 16 + quad * 4 + 3];
            #pragma unroll
            for (int dt = 0; dt < 8; ++dt) {
                o_acc[rb][dt][0] *= a0;
                o_acc[rb][dt][1] *= a1;
                o_acc[rb][dt][2] *= a2;
                o_acc[rb][dt][3] *= a3;
            }
        }
        short8 pf[4][2];
        #pragma unroll
        for (int rb = 0; rb < 4; ++rb)
            #pragma unroll
            for (int ks2 = 0; ks2 < 2; ++ks2)
                pf[rb][ks2] = *(const short8*)&Pb[(rb * 16 + l16) * 72 + ks2 * 32 + quad * 8];
        const u16* vp = vwave + kb;
        #pragma unroll
        for (int dt = 0; dt < 8; ++dt) {
            short8 vf0 = *(const short8*)(vp + (size_t)dt * 16 * SEQ);
            short8 vf1 = *(const short8*)(vp + (size_t)dt * 16 * SEQ + 32);
            #pragma unroll
            for (int rb = 0; rb < 4; ++rb) {
                o_acc[rb][dt] = __builtin_amdgcn_mfma_f32_16x16x32_bf16(pf[rb][0], vf0, o_acc[rb][dt], 0, 0, 0);
                o_acc[rb][dt] = __builtin_amdgcn_mfma_f32_16x16x32_bf16(pf[rb][1], vf1, o_acc[rb][dt], 0, 0, 0);
            }
        }
    }

    #pragma unroll
    for (int rb = 0; rb < 4; ++rb) {
        #pragma unroll
        for (int rr = 0; rr < 4; ++rr) {
            int row = rb * 16 + quad * 4 + rr;
            float linv = 1.f / l_st[row];
            #pragma unroll
            for (int dt = 0; dt < 8; ++dt) {
                out[((size_t)(b * SEQ + q0 + row)) * HD + w * 128 + dt * 16 + l16] =
                    o_acc[rb][dt][rr] * linv;
            }
        }
    }
}

extern "C" void kernel_launch(void* const* d_in, const int* in_sizes, int n_in,
                              void* d_out, int out_size, void* d_ws, size_t ws_size,
                              hipStream_t stream) {
    const float* x  = (const float*)d_in[0];
    const float* Wq = (const float*)d_in[1];
    const float* bq = (const float*)d_in[2];
    const float* Wk = (const float*)d_in[3];
    const float* bk = (const float*)d_in[4];
    const float* Wv = (const float*)d_in[5];
    const float* bv = (const float*)d_in[6];
    float* out = (float*)d_out;
    char* ws = (char*)d_ws;
    const size_t MB = 1024 * 1024;

    if (ws_size >= 224 * MB) {
        // Unfused path. Layout (peak 224 MB):
        //   vtb @0 (32MB) | qb @32 (32MB) | kb @64 (32MB) | S @96..224 (128MB)
        //   xb @96 (32MB, dead before S written) | wt @128 (6MB, dead too)
        u16* vtb = (u16*)ws;
        u16* qb  = (u16*)(ws + 32 * MB);
        u16* kb  = (u16*)(ws + 64 * MB);
        u16* S   = (u16*)(ws + 96 * MB);
        u16* xb  = (u16*)(ws + 96 * MB);
        u16* wt  = (u16*)(ws + 128 * MB);

        cvt_kernel<<<dim3(4096), 256, 0, stream>>>(x, xb, (4 * SEQ * HD) / 4);
        wt_kernel<<<dim3(16, 16, 3), 256, 0, stream>>>(Wq, Wk, Wv, wt);
        qkv_gemm<<<dim3(128, 8, 3), 256, 0, stream>>>(xb, wt, bq, bk, bv, qb, kb, vtb);
        gemm_s<<<dim3(4096), 256, 0, stream>>>(qb, kb, S);
        softmax_kernel<<<dim3(4096), 256, 0, stream>>>(S);
        gemm_o<<<dim3(1024), 256, 0, stream>>>(S, vtb, out);
    } else {
        // Fallback: proven flash path (134 MB).
        u16* xb  = (u16*)ws;
        u16* wt  = (u16*)(ws + 32 * MB);
        u16* qb  = (u16*)(ws + 38 * MB);
        u16* kb  = (u16*)(ws + 70 * MB);
        u16* vtb = (u16*)(ws + 102 * MB);

        cvt_kernel<<<dim3(4096), 256, 0, stream>>>(x, xb, (4 * SEQ * HD) / 4);
        wt_kernel<<<dim3(16, 16, 3), 256, 0, stream>>>(Wq, Wk, Wv, wt);
        qkv_gemm<<<dim3(128, 8, 3), 256, 0, stream>>>(xb, wt, bq, bk, bv, qb, kb, vtb);
        flash_kernel<<<dim3(256), 512, 0, stream>>>(qb, kb, vtb, out);
    }
}